// Round 8
// baseline (186.902 us; speedup 1.0000x reference)
//
#include <hip/hip_runtime.h>
#include <hip/hip_bf16.h>
#include <type_traits>

typedef unsigned short u16;
typedef __attribute__((ext_vector_type(2))) float f32x2;
typedef __attribute__((ext_vector_type(4))) float f32x4;
typedef __attribute__((ext_vector_type(8))) short short8;
typedef __attribute__((ext_vector_type(4))) short short4v;
typedef __attribute__((ext_vector_type(8))) __bf16 bf16x8;
typedef __attribute__((ext_vector_type(4))) __bf16 bf16x4;

#define BB 2
#define NN 2048
#define DDIM 1024
#define HH 8
#define QHH 16
#define DHH 64

__device__ __forceinline__ float b2f(u16 v) {
    return __builtin_bit_cast(float, ((unsigned)v) << 16);
}
__device__ __forceinline__ u16 f2b(float f) {
    unsigned u = __builtin_bit_cast(unsigned, f);
    u += 0x7FFFu + ((u >> 16) & 1u);   // RNE
    return (u16)(u >> 16);
}
__device__ __forceinline__ float fastrcp(float x) {
#if __has_builtin(__builtin_amdgcn_rcpf)
    return __builtin_amdgcn_rcpf(x);
#else
    return 1.0f / x;
#endif
}
__device__ __forceinline__ float fastexp2(float x) {
#if __has_builtin(__builtin_amdgcn_exp2f)
    return __builtin_amdgcn_exp2f(x);  // v_exp_f32; NB: __exp2f collides with glibc
#else
    return exp2f(x);
#endif
}
__device__ __forceinline__ f32x2 sp2(float v) { return (f32x2){v, v}; }
__device__ __forceinline__ f32x4 mfma16(short8 a, short8 b, f32x4 c) {
    return __builtin_amdgcn_mfma_f32_16x16x32_bf16(
        __builtin_bit_cast(bf16x8, a), __builtin_bit_cast(bf16x8, b), c, 0, 0, 0);
}
// K=16 MFMA: P^T (C-layout of S^T) is directly the B-operand (verified R9/R10)
#if __has_builtin(__builtin_amdgcn_mfma_f32_16x16x16_bf16)
__device__ __forceinline__ f32x4 mfma_k16(short4v a, short4v b, f32x4 c) {
    return __builtin_amdgcn_mfma_f32_16x16x16_bf16(
        __builtin_bit_cast(bf16x4, a), __builtin_bit_cast(bf16x4, b), c, 0, 0, 0);
}
#else
__device__ __forceinline__ f32x4 mfma_k16(short4v a, short4v b, f32x4 c) {
    return __builtin_amdgcn_mfma_f32_16x16x16bf16_1k(a, b, c, 0, 0, 0);
}
#endif
// async global->LDS, 16B/lane; dst = WAVE-UNIFORM base + lane*16 (m97 pattern)
__device__ __forceinline__ void stage16(const u16* g, u16* l, int lane) {
#if __has_builtin(__builtin_amdgcn_global_load_lds)
    __builtin_amdgcn_global_load_lds(
        (const __attribute__((address_space(1))) unsigned int*)g,
        (__attribute__((address_space(3))) unsigned int*)l, 16, 0, 0);
#else
    *(short8*)(l + lane * 8) = *(const short8*)g;
#endif
}

// ---------------- RMSNorm over tokens: [4096,1024] f32 -> bf16 ----------------
__global__ __launch_bounds__(256) void k_rmsnorm(const float* __restrict__ tokens,
                                                 const float* __restrict__ norm_w,
                                                 u16* __restrict__ xb) {
    const int row = blockIdx.x;
    const int tid = threadIdx.x;
    const float* xp = tokens + (size_t)row * DDIM + tid * 4;
    float4 raw = *(const float4*)xp;
    float ss = raw.x * raw.x + raw.y * raw.y + raw.z * raw.z + raw.w * raw.w;
#pragma unroll
    for (int d = 1; d < 64; d <<= 1) ss += __shfl_xor(ss, d);
    __shared__ float red[4];
    if ((tid & 63) == 0) red[tid >> 6] = ss;
    __syncthreads();
    float tot = red[0] + red[1] + red[2] + red[3];
    float r = rsqrtf(tot * (1.0f / 1024.0f) + 1.1920929e-7f);
    float4 wv = *(const float4*)(norm_w + tid * 4);
    ushort4 o;
    o.x = f2b(raw.x * r * wv.x);
    o.y = f2b(raw.y * r * wv.y);
    o.z = f2b(raw.z * r * wv.z);
    o.w = f2b(raw.w * r * wv.w);
    *(ushort4*)(xb + (size_t)row * DDIM + tid * 4) = o;
}

// ---------------- batched weight transpose f32 [R,C] -> bf16 [C,R]; z selects matrix ----------------
__global__ __launch_bounds__(256) void k_wprep(const float* __restrict__ Wq,
                                               const float* __restrict__ Wkv,
                                               const float* __restrict__ Wout,
                                               u16* __restrict__ WqT,
                                               u16* __restrict__ WkvT,
                                               u16* __restrict__ WoutT) {
    const int z = blockIdx.z;
    const float* in = (z == 0) ? Wq : (z == 1) ? Wkv : Wout;
    u16* out = (z == 0) ? WqT : (z == 1) ? WkvT : WoutT;
    const int R = (z == 2) ? 512 : 1024, C = 1024;
    const int br = blockIdx.y * 32;
    if (br >= R) return;
    __shared__ u16 tile[32][33];
    const int bc = blockIdx.x * 32;
    const int tx = threadIdx.x & 31, ty = threadIdx.x >> 5;
#pragma unroll
    for (int i = 0; i < 32; i += 8) tile[ty + i][tx] = f2b(in[(size_t)(br + ty + i) * C + bc + tx]);
    __syncthreads();
#pragma unroll
    for (int i = 0; i < 32; i += 8) out[(size_t)(bc + ty + i) * R + br + tx] = tile[tx][ty + i];
}

// ---------------- GEMM 128x128 (m97-style): C[M,N] = A[M,K] x Bt[N,K], async staging,
// 4 waves x (4x4) 16x16x32 frags = 16 MFMA/wave/k-step ----------------
__global__ __launch_bounds__(256) void k_gemm128(const u16* __restrict__ A,
                                                 const u16* __restrict__ Bt,
                                                 u16* __restrict__ C,
                                                 int M, int Ncols, int K) {
    __shared__ __attribute__((aligned(16))) u16 As[128 * 32];
    __shared__ __attribute__((aligned(16))) u16 Bs[128 * 32];
    const int tid = threadIdx.x;
    const int lane = tid & 63;
    const int w = tid >> 6;
    const int m0 = blockIdx.y * 128;
    const int n0 = blockIdx.x * 128;
    const int wr = (w >> 1) * 64;
    const int wc = (w & 1) * 64;
    const int lr = lane & 15;
    const int lq = lane >> 4;

    // wave w stages rows [w*32, w*32+32) of As and Bs (two 16-row stage16 calls each)
    const int ch0 = w * 32;
    const u16* aSrc = A + (size_t)(m0 + ch0 + (lane >> 2)) * K + (lane & 3) * 8;
    const u16* bSrc = Bt + (size_t)(n0 + ch0 + (lane >> 2)) * K + (lane & 3) * 8;
    u16* aDst = As + ch0 * 32;
    u16* bDst = Bs + ch0 * 32;

    f32x4 acc[4][4];
#pragma unroll
    for (int i = 0; i < 4; i++)
#pragma unroll
        for (int j = 0; j < 4; j++) acc[i][j] = (f32x4){0.f, 0.f, 0.f, 0.f};

    for (int k0 = 0; k0 < K; k0 += 32) {
        __syncthreads();
        stage16(aSrc, aDst, lane);
        stage16(aSrc + (size_t)16 * K, aDst + 512, lane);
        stage16(bSrc, bDst, lane);
        stage16(bSrc + (size_t)16 * K, bDst + 512, lane);
        aSrc += 32;
        bSrc += 32;
        __syncthreads();
        short8 a[4], b[4];
#pragma unroll
        for (int mi = 0; mi < 4; ++mi) a[mi] = *(const short8*)&As[(wr + mi * 16 + lr) * 32 + lq * 8];
#pragma unroll
        for (int ni = 0; ni < 4; ++ni) b[ni] = *(const short8*)&Bs[(wc + ni * 16 + lr) * 32 + lq * 8];
#pragma unroll
        for (int mi = 0; mi < 4; ++mi)
#pragma unroll
            for (int ni = 0; ni < 4; ++ni) acc[mi][ni] = mfma16(a[mi], b[ni], acc[mi][ni]);
    }
#pragma unroll
    for (int mi = 0; mi < 4; ++mi)
#pragma unroll
        for (int ni = 0; ni < 4; ++ni)
#pragma unroll
            for (int r = 0; r < 4; ++r) {
                int row = m0 + wr + mi * 16 + lq * 4 + r;
                int col = n0 + wc + ni * 16 + lr;
                C[(size_t)row * Ncols + col] = f2b(acc[mi][ni][r]);
            }
}

// ---------------- GEMM 64x128: f32 out (final out-proj) ----------------
__global__ __launch_bounds__(256) void k_gemm64f(const u16* __restrict__ A,
                                                 const u16* __restrict__ Bt,
                                                 float* __restrict__ C,
                                                 int M, int Ncols, int K) {
    __shared__ __attribute__((aligned(16))) u16 As[64 * 32];
    __shared__ __attribute__((aligned(16))) u16 Bs[128 * 32];
    const int tid = threadIdx.x;
    const int lane = tid & 63;
    const int w = tid >> 6;
    const int m0 = blockIdx.y * 64;
    const int n0 = blockIdx.x * 128;
    const int lr = lane & 15;
    const int lq = lane >> 4;

    const u16* aSrc = A + (size_t)(m0 + w * 16 + (lane >> 2)) * K + (lane & 3) * 8;
    const u16* bSrc = Bt + (size_t)(n0 + w * 32 + (lane >> 2)) * K + (lane & 3) * 8;
    u16* aDst = As + w * 16 * 32;
    u16* bDst = Bs + w * 32 * 32;

    f32x4 acc[8];
#pragma unroll
    for (int i = 0; i < 8; i++) acc[i] = (f32x4){0.f, 0.f, 0.f, 0.f};

    for (int k0 = 0; k0 < K; k0 += 32) {
        __syncthreads();
        stage16(aSrc, aDst, lane);
        stage16(bSrc, bDst, lane);
        stage16(bSrc + (size_t)16 * K, bDst + 512, lane);
        aSrc += 32;
        bSrc += 32;
        __syncthreads();
        short8 a = *(const short8*)&As[(w * 16 + lr) * 32 + lq * 8];
#pragma unroll
        for (int nt = 0; nt < 8; ++nt) {
            short8 b = *(const short8*)&Bs[(nt * 16 + lr) * 32 + lq * 8];
            acc[nt] = mfma16(a, b, acc[nt]);
        }
    }
#pragma unroll
    for (int nt = 0; nt < 8; ++nt)
#pragma unroll
        for (int r = 0; r < 4; ++r) {
            int row = m0 + w * 16 + lq * 4 + r;
            int col = n0 + nt * 16 + lr;
            C[(size_t)row * Ncols + col] = acc[nt][r];
        }
}

// ---------------- per-head L2 norm + scale from FUSED qkv [4096][2048]; emit qn, kn ----------------
// NOTE: kn carries the softcap pre-scale 1/50 folded in (kn only feeds QK^T):
//   k scale = (g+1)*8*0.02 = (g+1)*0.16  =>  S^T from MFMA is directly x = sim/50.
__global__ __launch_bounds__(256) void k_headnorm(const u16* __restrict__ qkv,
                                                  const float* __restrict__ q_gamma,
                                                  const float* __restrict__ k_gamma,
                                                  u16* __restrict__ qn,
                                                  u16* __restrict__ kn) {
    const int row = blockIdx.x;  // b*N + n
    const int b = row >> 11, n = row & 2047;
    const int lane = threadIdx.x & 63, w = threadIdx.x >> 6;
    const u16* qr = qkv + (size_t)row * 2048;
    const u16* kvr = qkv + (size_t)row * 2048 + 1024;
#pragma unroll
    for (int t = 0; t < 4; ++t) {
        int qh = w * 4 + t;
        float v = b2f(qr[qh * 64 + lane]);
        float ss = v * v;
#pragma unroll
        for (int d = 1; d < 64; d <<= 1) ss += __shfl_xor(ss, d);
        float nrm = fmaxf(sqrtf(ss), 1e-12f);
        float g = q_gamma[qh * 64 + lane];
        qn[((size_t)(b * QHH + qh) * NN + n) * 64 + lane] = f2b(v / nrm * (g + 1.0f) * 8.0f);
    }
#pragma unroll
    for (int t = 0; t < 2; ++t) {
        int kh = w * 2 + t;
        float v = b2f(kvr[kh * 64 + lane]);
        float ss = v * v;
#pragma unroll
        for (int d = 1; d < 64; d <<= 1) ss += __shfl_xor(ss, d);
        float nrm = fmaxf(sqrtf(ss), 1e-12f);
        float g = k_gamma[kh * 64 + lane];
        kn[((size_t)(b * HH + kh) * NN + n) * 64 + lane] = f2b(v / nrm * (g + 1.0f) * 0.16f);
    }
}

// ---------------- V transpose via LDS, fully coalesced both sides:
// vt[b,h][d][n] from fused qkv rows (v-part at +1536).
// R17: rows with (d&8) store each aligned 16B n-chunk with its 8B halves
// SWAPPED. Combined with the reader's half-select (lq^(lr>>3))&1, the PV
// vf reads hit 16 distinct 8B slots per 16-lane group -> bank-conflict-free. ----------------
__global__ __launch_bounds__(256) void k_vtrans(const u16* __restrict__ qkv,
                                                u16* __restrict__ vt) {
    const int bh = blockIdx.x;           // b*8+h
    const int b = bh >> 3, h = bh & 7;
    const int n0 = blockIdx.y * 64;
    const int tid = threadIdx.x;
    __shared__ u16 t[64 * 72];           // row pad 72 keeps 16B-aligned rows, breaks bank stride
#pragma unroll
    for (int it = 0; it < 2; ++it) {
        int idx = tid + it * 256;        // 512 chunks: row i = idx>>3, chunk c = idx&7
        int i = idx >> 3, c = idx & 7;
        short8 v = *(const short8*)&qkv[(size_t)(b * NN + n0 + i) * 2048 + 1536 + h * 64 + c * 8];
        *(short8*)&t[i * 72 + c * 8] = v;
    }
    __syncthreads();
#pragma unroll
    for (int it = 0; it < 2; ++it) {
        int idx = tid + it * 256;        // d = idx>>3, n-chunk c = idx&7
        int d = idx >> 3, c = idx & 7;
        const int sw = (d >> 3) & 1;     // half-swap for d&8 rows
        u16 tmp[8], o[8];
#pragma unroll
        for (int j = 0; j < 8; ++j) tmp[j] = t[(c * 8 + j) * 72 + d];
#pragma unroll
        for (int j = 0; j < 8; ++j) o[j] = tmp[j ^ (sw << 2)];
        *(short8*)&vt[((size_t)(bh * 64 + d)) * NN + n0 + c * 8] = *(short8*)o;
    }
}

// ---------------- flash attention v16: CAUSAL SPLIT-J (flash-decoding style).
// Fixed-max softmax => partials over disjoint j-ranges combine EXACTLY linearly:
// O = (Oa+Ob)/(la+lb). Each (bq, z) strip -> 2 blocks: s=0 j-tiles [0,jmid),
// s=1 [jmid,ntile). Grid 32x64 = 2048 blocks -> 5 resident/CU (LDS-capped)
// = 20 waves/CU (was 16 nominal / 9 effective). Blocks write unnormalized bf16
// O-partials (n-major) + per-row l-partials; k_gsum normalizes+combines.
// Keeps R17: conflict-free vf (vt half-swap), setprio, packed-poly softmax. ----------------
__global__ __launch_bounds__(256) void k_attn(const u16* __restrict__ qn,
                                              const u16* __restrict__ kn,
                                              const u16* __restrict__ vt,
                                              u16* __restrict__ OT,
                                              float* __restrict__ Lp) {
    const int bq = blockIdx.x;  // b*16+qh
    const int b = bq >> 4, qh = bq & 15;
    const int h = qh >> 1;
    const int tid = threadIdx.x;
    const int lane = tid & 63, w = tid >> 6;
    const int lr = lane & 15, lq = lane >> 4;
    const int y = blockIdx.y;
    const int z = 31 - (y >> 1);     // LPT: heaviest strips first
    const int s = y & 1;             // j-split half
    const int ntile = z + 1;
    const int jmid = (ntile + 1) >> 1;
    const int jb = s ? jmid : 0;
    const int je = s ? ntile : jmid;
    const int ntl = je - jb;
    const int i0 = z * 64 + w * 16;
    const int irow = i0 + lr;

    const u16* Qp = qn + (size_t)(b * QHH + qh) * NN * 64;
    const u16* Kp = kn + (size_t)(b * HH + h) * NN * 64;
    const u16* Vp = vt + (size_t)(b * HH + h) * 64 * NN;
    u16* Op = OT + (size_t)s * (BB * QHH * NN * 64) + (size_t)bq * NN * 64;  // [s][bq][n][d]
    float* Lsel = Lp + (size_t)s * (BB * QHH * NN) + (size_t)bq * NN;        // [s][bq][n]

    __shared__ __attribute__((aligned(16))) u16 Ks[2][64 * 64];
    __shared__ __attribute__((aligned(16))) u16 Vs[2][64 * 64];

    short8 qf0 = *(const short8*)&Qp[(size_t)(i0 + lr) * 64 + lq * 8];
    short8 qf1 = *(const short8*)&Qp[(size_t)(i0 + lr) * 64 + 32 + lq * 8];

    f32x4 of[4];
#pragma unroll
    for (int dt = 0; dt < 4; ++dt) of[dt] = (f32x4){0.f, 0.f, 0.f, 0.f};
    f32x2 ls = {0.f, 0.f};

    const int srow = lane >> 3;
    const int sch = (lane ^ srow) & 7;
    const int rA = w * 16, rB = w * 16 + 8;

    // incremental staging pointers, pre-offset to tile jb
    const u16* kSrcA = Kp + (size_t)jb * 4096 + (size_t)(rA + srow) * 64 + sch * 8;
    const u16* kSrcB = Kp + (size_t)jb * 4096 + (size_t)(rB + srow) * 64 + sch * 8;
    const u16* vSrcA = Vp + (size_t)(rA + srow) * NN + jb * 64 + sch * 8;
    const u16* vSrcB = Vp + (size_t)(rB + srow) * NN + jb * 64 + sch * 8;

    auto stageKV = [&](int buf) {
        stage16(kSrcA, &Ks[buf][rA * 64], lane);
        stage16(kSrcB, &Ks[buf][rB * 64], lane);
        stage16(vSrcA, &Vs[buf][rA * 64], lane);
        stage16(vSrcB, &Vs[buf][rB * 64], lane);
        kSrcA += 64 * 64;
        kSrcB += 64 * 64;
        vSrcA += 64;
        vSrcB += 64;
    };

    // softmax on one 4-elem score fragment: x=sim/50 pre-folded; p=exp2(G(x^2)*x - c)
    auto smax = [&](f32x4 sc, int lim, bool masked) -> short4v {
        f32x2 xa = {sc[0], sc[1]};
        f32x2 xb = {sc[2], sc[3]};
        f32x2 ya = xa * xa;
        f32x2 yb = xb * xb;
        f32x2 Ga = __builtin_elementwise_fma(ya, __builtin_elementwise_fma(ya,
                       __builtin_elementwise_fma(ya, __builtin_elementwise_fma(ya,
                           sp2(0.04705711f), sp2(-0.32327190f)), sp2(1.11500760f)),
                       sp2(-2.98719110f)), sp2(9.01599730f));
        f32x2 Gb = __builtin_elementwise_fma(yb, __builtin_elementwise_fma(yb,
                       __builtin_elementwise_fma(yb, __builtin_elementwise_fma(yb,
                           sp2(0.04705711f), sp2(-0.32327190f)), sp2(1.11500760f)),
                       sp2(-2.98719110f)), sp2(9.01599730f));
        f32x2 aa = __builtin_elementwise_fma(xa, Ga, sp2(-9.0168440f));
        f32x2 ab = __builtin_elementwise_fma(xb, Gb, sp2(-9.0168440f));
        float p0 = fastexp2(aa.x);
        float p1 = fastexp2(aa.y);
        float p2 = fastexp2(ab.x);
        float p3 = fastexp2(ab.y);
        if (masked) {
            p0 = (0 <= lim) ? p0 : 0.0f;
            p1 = (1 <= lim) ? p1 : 0.0f;
            p2 = (2 <= lim) ? p2 : 0.0f;
            p3 = (3 <= lim) ? p3 : 0.0f;
        }
        ls += (f32x2){p0, p1};
        ls += (f32x2){p2, p3};
        bf16x4 pb;
        pb[0] = (__bf16)p0;
        pb[1] = (__bf16)p1;
        pb[2] = (__bf16)p2;
        pb[3] = (__bf16)p3;
        return __builtin_bit_cast(short4v, pb);
    };

    auto tile = [&](int buf, int jt) {
        const int j0 = jt << 6;
        const u16* kb = &Ks[buf][0];
        const u16* vb = &Vs[buf][0];
        f32x4 sc[4];
        __builtin_amdgcn_s_setprio(1);
#pragma unroll
        for (int ct = 0; ct < 4; ++ct) {
            const int r = ct * 16 + lr;
            short8 kf0 = *(const short8*)&kb[r * 64 + ((lq ^ (lr & 7)) << 3)];
            short8 kf1 = *(const short8*)&kb[r * 64 + (((4 + lq) ^ (lr & 7)) << 3)];
            f32x4 t = (f32x4){0.f, 0.f, 0.f, 0.f};
            t = mfma16(kf0, qf0, t);
            t = mfma16(kf1, qf1, t);
            sc[ct] = t;
        }
        __builtin_amdgcn_s_setprio(0);
        const bool masked = (jt == ntile - 1);
        short4v pk[4];
#pragma unroll
        for (int ct = 0; ct < 4; ++ct) {
            const int lim = irow - (j0 + ct * 16 + lq * 4);
            pk[ct] = smax(sc[ct], lim, masked);
        }
        __builtin_amdgcn_s_setprio(1);
#pragma unroll
        for (int dt = 0; dt < 4; ++dt) {
            const int d = dt * 16 + lr;
#pragma unroll
            for (int ct = 0; ct < 4; ++ct) {
                // half-select (lq^(lr>>3))&1 pairs with vtrans's d&8 half-swap:
                // 16 lanes per (g,lq-parity) group hit 16 distinct 8B slots.
                short4v vf = *(const short4v*)
                    &vb[d * 64 + ((((ct << 1) + (lq >> 1)) ^ (lr & 7)) << 3) +
                        (((lq ^ (lr >> 3)) & 1) << 2)];
                of[dt] = mfma_k16(vf, pk[ct], of[dt]);
            }
        }
        __builtin_amdgcn_s_setprio(0);
    };

    if (ntl > 0) {
        stageKV(0);
        for (int t = 0; t < ntl; ++t) {
            const int buf = t & 1;
            __syncthreads();
            if (t + 1 < ntl) stageKV(buf ^ 1);
            tile(buf, jb + t);
        }
    }

    float l = ls.x + ls.y;
    l += __shfl_xor(l, 16);
    l += __shfl_xor(l, 32);
    // write UNNORMALIZED partial O (bf16, n-major) + partial l (one per row)
#pragma unroll
    for (int dt = 0; dt < 4; ++dt) {
        u16 o[4];
#pragma unroll
        for (int r = 0; r < 4; ++r) o[r] = f2b(of[dt][r]);
        *(ushort4*)&Op[(size_t)irow * 64 + dt * 16 + lq * 4] = *(ushort4*)o;
    }
    if (lq == 0) Lsel[irow] = l;
}

// ---------------- combine splits+groups (n-major partials):
// AO[b,n,hh*64+d] = (Oa0+Ob0)/(la0+lb0) + (Oa1+Ob1)/(la1+lb1)
// fully coalesced elementwise, no LDS ----------------
__global__ __launch_bounds__(256) void k_gsum(const u16* __restrict__ O,
                                              const float* __restrict__ Lp,
                                              u16* __restrict__ AO) {
    const int idx = blockIdx.x * 256 + threadIdx.x;   // 8B chunk id: [b][n][c8]
    const int c8 = idx & 63;
    const int n = (idx >> 6) & 2047;
    const int b = idx >> 17;
    const int hh = c8 >> 3;
    const int ch = c8 & 7;
    const int q0 = b * QHH + 2 * hh, q1 = q0 + 1;
    const size_t SOFF = (size_t)BB * QHH * NN * 64;   // s=1 O offset (u16 units)
    const size_t LOFF = (size_t)BB * QHH * NN;        // s=1 L offset (floats)
    const u16* a0 = O + ((size_t)q0 * NN + n) * 64 + ch * 8;
    const u16* a1 = O + ((size_t)q1 * NN + n) * 64 + ch * 8;
    const u16* b0 = a0 + SOFF;
    const u16* b1 = a1 + SOFF;
    const float l0 = Lp[(size_t)q0 * NN + n] + Lp[LOFF + (size_t)q0 * NN + n];
    const float l1 = Lp[(size_t)q1 * NN + n] + Lp[LOFF + (size_t)q1 * NN + n];
    const float inv0 = fastrcp(l0);
    const float inv1 = fastrcp(l1);
    short8 va0 = *(const short8*)a0;
    short8 vb0 = *(const short8*)b0;
    short8 va1 = *(const short8*)a1;
    short8 vb1 = *(const short8*)b1;
    u16 o[8];
#pragma unroll
    for (int j = 0; j < 8; ++j)
        o[j] = f2b((b2f((u16)va0[j]) + b2f((u16)vb0[j])) * inv0 +
                   (b2f((u16)va1[j]) + b2f((u16)vb1[j])) * inv1);
    *(short8*)&AO[((size_t)(b * NN + n)) * 512 + c8 * 8] = *(short8*)o;
}

extern "C" void kernel_launch(void* const* d_in, const int* in_sizes, int n_in,
                              void* d_out, int out_size, void* d_ws, size_t ws_size,
                              hipStream_t stream) {
    const float* tokens = (const float*)d_in[0];
    const float* norm_w = (const float*)d_in[1];
    const float* Wq = (const float*)d_in[2];
    const float* Wkv = (const float*)d_in[3];
    const float* Wout = (const float*)d_in[4];
    const float* q_gamma = (const float*)d_in[5];
    const float* k_gamma = (const float*)d_in[6];
    float* out = (float*)d_out;

    char* ws = (char*)d_ws;
    u16* xb = (u16*)(ws + 0);             // 8 MB  [4096,1024]
    u16* WqT = (u16*)(ws + 8388608);      // 2 MB  } adjacent => fused Bt [2048][1024]
    u16* WkvT = (u16*)(ws + 10485760);    // 2 MB  }
    u16* WoutT = (u16*)(ws + 12582912);   // 1 MB
    u16* qkv = (u16*)(ws + 13631488);     // 16 MB fused [4096][2048] (q_raw ∪ kv_raw)
    u16* kn = (u16*)(ws + 30408704);      // 4 MB
    u16* vtb = (u16*)(ws + 34603008);     // 4 MB
    // Lifetime aliases (stream-ordered, no overlap):
    u16* qn = xb;                       // xb dead after fused QKV GEMM
    u16* Opart = qkv;                   // 16 MB: [s=0]8MB @13631488 + [s=1]8MB @22020096 (qkv dead)
    float* Lpart = (float*)(ws + 8388608);  // 512 KB in dead WqT/WkvT region (dead after gemm128)
    u16* AO = kn;                       // 4 MB: kn dead after attn; AO written by gsum after attn

    k_rmsnorm<<<4096, 256, 0, stream>>>(tokens, norm_w, xb);
    k_wprep<<<dim3(32, 32, 3), 256, 0, stream>>>(Wq, Wkv, Wout, WqT, WkvT, WoutT);
    // fused QKV GEMM: [4096,1024] x [2048,1024]^T -> [4096,2048]
    k_gemm128<<<dim3(16, 32), 256, 0, stream>>>(xb, WqT, qkv, 4096, 2048, 1024);
    k_headnorm<<<4096, 256, 0, stream>>>(qkv, q_gamma, k_gamma, qn, kn);
    k_vtrans<<<dim3(16, 32), 256, 0, stream>>>(qkv, vtb);
    k_attn<<<dim3(32, 64), 256, 0, stream>>>(qn, kn, vtb, Opart, Lpart);
    k_gsum<<<1024, 256, 0, stream>>>(Opart, Lpart, AO);
    k_gemm64f<<<dim3(8, 64), 256, 0, stream>>>(AO, WoutT, out, 4096, 1024, 512);
}

// Round 9
// 180.265 us; speedup vs baseline: 1.0368x; 1.0368x over previous
//
#include <hip/hip_runtime.h>
#include <hip/hip_bf16.h>
#include <type_traits>

typedef unsigned short u16;
typedef __attribute__((ext_vector_type(2))) float f32x2;
typedef __attribute__((ext_vector_type(4))) float f32x4;
typedef __attribute__((ext_vector_type(8))) short short8;
typedef __attribute__((ext_vector_type(4))) short short4v;
typedef __attribute__((ext_vector_type(8))) __bf16 bf16x8;
typedef __attribute__((ext_vector_type(4))) __bf16 bf16x4;

#define BB 2
#define NN 2048
#define DDIM 1024
#define HH 8
#define QHH 16
#define DHH 64

__device__ __forceinline__ float b2f(u16 v) {
    return __builtin_bit_cast(float, ((unsigned)v) << 16);
}
__device__ __forceinline__ u16 f2b(float f) {
    unsigned u = __builtin_bit_cast(unsigned, f);
    u += 0x7FFFu + ((u >> 16) & 1u);   // RNE
    return (u16)(u >> 16);
}
__device__ __forceinline__ float fastrcp(float x) {
#if __has_builtin(__builtin_amdgcn_rcpf)
    return __builtin_amdgcn_rcpf(x);
#else
    return 1.0f / x;
#endif
}
__device__ __forceinline__ float fastexp2(float x) {
#if __has_builtin(__builtin_amdgcn_exp2f)
    return __builtin_amdgcn_exp2f(x);  // v_exp_f32; NB: __exp2f collides with glibc
#else
    return exp2f(x);
#endif
}
__device__ __forceinline__ f32x2 sp2(float v) { return (f32x2){v, v}; }
__device__ __forceinline__ f32x4 mfma16(short8 a, short8 b, f32x4 c) {
    return __builtin_amdgcn_mfma_f32_16x16x32_bf16(
        __builtin_bit_cast(bf16x8, a), __builtin_bit_cast(bf16x8, b), c, 0, 0, 0);
}
// K=16 MFMA: P^T (C-layout of S^T) is directly the B-operand (verified R9/R10)
#if __has_builtin(__builtin_amdgcn_mfma_f32_16x16x16_bf16)
__device__ __forceinline__ f32x4 mfma_k16(short4v a, short4v b, f32x4 c) {
    return __builtin_amdgcn_mfma_f32_16x16x16_bf16(
        __builtin_bit_cast(bf16x4, a), __builtin_bit_cast(bf16x4, b), c, 0, 0, 0);
}
#else
__device__ __forceinline__ f32x4 mfma_k16(short4v a, short4v b, f32x4 c) {
    return __builtin_amdgcn_mfma_f32_16x16x16bf16_1k(a, b, c, 0, 0, 0);
}
#endif
// async global->LDS, 16B/lane; dst = WAVE-UNIFORM base + lane*16 (m97 pattern)
__device__ __forceinline__ void stage16(const u16* g, u16* l, int lane) {
#if __has_builtin(__builtin_amdgcn_global_load_lds)
    __builtin_amdgcn_global_load_lds(
        (const __attribute__((address_space(1))) unsigned int*)g,
        (__attribute__((address_space(3))) unsigned int*)l, 16, 0, 0);
#else
    *(short8*)(l + lane * 8) = *(const short8*)g;
#endif
}

// ---------------- FUSED pre-pass: rmsnorm (blocks 0..4095) + weight transpose
// (blocks 4096..7167). Independent work, one launch. ----------------
__global__ __launch_bounds__(256) void k_pre(const float* __restrict__ tokens,
                                             const float* __restrict__ norm_w,
                                             u16* __restrict__ xb,
                                             const float* __restrict__ Wq,
                                             const float* __restrict__ Wkv,
                                             const float* __restrict__ Wout,
                                             u16* __restrict__ WqT,
                                             u16* __restrict__ WkvT,
                                             u16* __restrict__ WoutT) {
    __shared__ float red[4];
    __shared__ u16 tile[32][33];
    const int bid = blockIdx.x;
    const int tid = threadIdx.x;
    if (bid < 4096) {
        // ---- RMSNorm row ----
        const int row = bid;
        const float* xp = tokens + (size_t)row * DDIM + tid * 4;
        float4 raw = *(const float4*)xp;
        float ss = raw.x * raw.x + raw.y * raw.y + raw.z * raw.z + raw.w * raw.w;
#pragma unroll
        for (int d = 1; d < 64; d <<= 1) ss += __shfl_xor(ss, d);
        if ((tid & 63) == 0) red[tid >> 6] = ss;
        __syncthreads();
        float tot = red[0] + red[1] + red[2] + red[3];
        float r = rsqrtf(tot * (1.0f / 1024.0f) + 1.1920929e-7f);
        float4 wv = *(const float4*)(norm_w + tid * 4);
        ushort4 o;
        o.x = f2b(raw.x * r * wv.x);
        o.y = f2b(raw.y * r * wv.y);
        o.z = f2b(raw.z * r * wv.z);
        o.w = f2b(raw.w * r * wv.w);
        *(ushort4*)(xb + (size_t)row * DDIM + tid * 4) = o;
    } else {
        // ---- weight transpose tile ----
        const int idx = bid - 4096;
        const int z = idx >> 10;
        const int rem = idx & 1023;
        const int by = rem >> 5, bx = rem & 31;
        const float* in = (z == 0) ? Wq : (z == 1) ? Wkv : Wout;
        u16* out = (z == 0) ? WqT : (z == 1) ? WkvT : WoutT;
        const int R = (z == 2) ? 512 : 1024, C = 1024;
        const int br = by * 32;
        if (br >= R) return;
        const int bc = bx * 32;
        const int tx = tid & 31, ty = tid >> 5;
#pragma unroll
        for (int i = 0; i < 32; i += 8)
            tile[ty + i][tx] = f2b(in[(size_t)(br + ty + i) * C + bc + tx]);
        __syncthreads();
#pragma unroll
        for (int i = 0; i < 32; i += 8)
            out[(size_t)(bc + ty + i) * R + br + tx] = tile[tx][ty + i];
    }
}

// ---------------- GEMM 128x128 (m97-style): C[M,N] = A[M,K] x Bt[N,K], async staging,
// 4 waves x (4x4) 16x16x32 frags = 16 MFMA/wave/k-step ----------------
__global__ __launch_bounds__(256) void k_gemm128(const u16* __restrict__ A,
                                                 const u16* __restrict__ Bt,
                                                 u16* __restrict__ C,
                                                 int M, int Ncols, int K) {
    __shared__ __attribute__((aligned(16))) u16 As[128 * 32];
    __shared__ __attribute__((aligned(16))) u16 Bs[128 * 32];
    const int tid = threadIdx.x;
    const int lane = tid & 63;
    const int w = tid >> 6;
    const int m0 = blockIdx.y * 128;
    const int n0 = blockIdx.x * 128;
    const int wr = (w >> 1) * 64;
    const int wc = (w & 1) * 64;
    const int lr = lane & 15;
    const int lq = lane >> 4;

    // wave w stages rows [w*32, w*32+32) of As and Bs (two 16-row stage16 calls each)
    const int ch0 = w * 32;
    const u16* aSrc = A + (size_t)(m0 + ch0 + (lane >> 2)) * K + (lane & 3) * 8;
    const u16* bSrc = Bt + (size_t)(n0 + ch0 + (lane >> 2)) * K + (lane & 3) * 8;
    u16* aDst = As + ch0 * 32;
    u16* bDst = Bs + ch0 * 32;

    f32x4 acc[4][4];
#pragma unroll
    for (int i = 0; i < 4; i++)
#pragma unroll
        for (int j = 0; j < 4; j++) acc[i][j] = (f32x4){0.f, 0.f, 0.f, 0.f};

    for (int k0 = 0; k0 < K; k0 += 32) {
        __syncthreads();
        stage16(aSrc, aDst, lane);
        stage16(aSrc + (size_t)16 * K, aDst + 512, lane);
        stage16(bSrc, bDst, lane);
        stage16(bSrc + (size_t)16 * K, bDst + 512, lane);
        aSrc += 32;
        bSrc += 32;
        __syncthreads();
        short8 a[4], b[4];
#pragma unroll
        for (int mi = 0; mi < 4; ++mi) a[mi] = *(const short8*)&As[(wr + mi * 16 + lr) * 32 + lq * 8];
#pragma unroll
        for (int ni = 0; ni < 4; ++ni) b[ni] = *(const short8*)&Bs[(wc + ni * 16 + lr) * 32 + lq * 8];
#pragma unroll
        for (int mi = 0; mi < 4; ++mi)
#pragma unroll
            for (int ni = 0; ni < 4; ++ni) acc[mi][ni] = mfma16(a[mi], b[ni], acc[mi][ni]);
    }
#pragma unroll
    for (int mi = 0; mi < 4; ++mi)
#pragma unroll
        for (int ni = 0; ni < 4; ++ni)
#pragma unroll
            for (int r = 0; r < 4; ++r) {
                int row = m0 + wr + mi * 16 + lq * 4 + r;
                int col = n0 + wc + ni * 16 + lr;
                C[(size_t)row * Ncols + col] = f2b(acc[mi][ni][r]);
            }
}

// ---------------- GEMM 64x128: f32 out (final out-proj) ----------------
__global__ __launch_bounds__(256) void k_gemm64f(const u16* __restrict__ A,
                                                 const u16* __restrict__ Bt,
                                                 float* __restrict__ C,
                                                 int M, int Ncols, int K) {
    __shared__ __attribute__((aligned(16))) u16 As[64 * 32];
    __shared__ __attribute__((aligned(16))) u16 Bs[128 * 32];
    const int tid = threadIdx.x;
    const int lane = tid & 63;
    const int w = tid >> 6;
    const int m0 = blockIdx.y * 64;
    const int n0 = blockIdx.x * 128;
    const int lr = lane & 15;
    const int lq = lane >> 4;

    const u16* aSrc = A + (size_t)(m0 + w * 16 + (lane >> 2)) * K + (lane & 3) * 8;
    const u16* bSrc = Bt + (size_t)(n0 + w * 32 + (lane >> 2)) * K + (lane & 3) * 8;
    u16* aDst = As + w * 16 * 32;
    u16* bDst = Bs + w * 32 * 32;

    f32x4 acc[8];
#pragma unroll
    for (int i = 0; i < 8; i++) acc[i] = (f32x4){0.f, 0.f, 0.f, 0.f};

    for (int k0 = 0; k0 < K; k0 += 32) {
        __syncthreads();
        stage16(aSrc, aDst, lane);
        stage16(bSrc, bDst, lane);
        stage16(bSrc + (size_t)16 * K, bDst + 512, lane);
        aSrc += 32;
        bSrc += 32;
        __syncthreads();
        short8 a = *(const short8*)&As[(w * 16 + lr) * 32 + lq * 8];
#pragma unroll
        for (int nt = 0; nt < 8; ++nt) {
            short8 b = *(const short8*)&Bs[(nt * 16 + lr) * 32 + lq * 8];
            acc[nt] = mfma16(a, b, acc[nt]);
        }
    }
#pragma unroll
    for (int nt = 0; nt < 8; ++nt)
#pragma unroll
        for (int r = 0; r < 4; ++r) {
            int row = m0 + w * 16 + lq * 4 + r;
            int col = n0 + nt * 16 + lr;
            C[(size_t)row * Ncols + col] = acc[nt][r];
        }
}

// ---------------- FUSED mid-pass: per-head norm (blocks 0..4095) + V transpose
// (blocks 4096..4607). Both read qkv; independent outputs. ----------------
// kn carries softcap pre-scale: (g+1)*8*0.02 = (g+1)*0.16.
// vtrans half-swaps 8B halves on d&8 rows (pairs with attn reader's half-select).
__global__ __launch_bounds__(256) void k_mid(const u16* __restrict__ qkv,
                                             const float* __restrict__ q_gamma,
                                             const float* __restrict__ k_gamma,
                                             u16* __restrict__ qn,
                                             u16* __restrict__ kn,
                                             u16* __restrict__ vt) {
    __shared__ u16 t[64 * 72];
    const int bid = blockIdx.x;
    const int tid = threadIdx.x;
    if (bid < 4096) {
        const int row = bid;  // b*N + n
        const int b = row >> 11, n = row & 2047;
        const int lane = tid & 63, w = tid >> 6;
        const u16* qr = qkv + (size_t)row * 2048;
        const u16* kvr = qkv + (size_t)row * 2048 + 1024;
#pragma unroll
        for (int tq = 0; tq < 4; ++tq) {
            int qh = w * 4 + tq;
            float v = b2f(qr[qh * 64 + lane]);
            float ss = v * v;
#pragma unroll
            for (int d = 1; d < 64; d <<= 1) ss += __shfl_xor(ss, d);
            float nrm = fmaxf(sqrtf(ss), 1e-12f);
            float g = q_gamma[qh * 64 + lane];
            qn[((size_t)(b * QHH + qh) * NN + n) * 64 + lane] = f2b(v / nrm * (g + 1.0f) * 8.0f);
        }
#pragma unroll
        for (int tk = 0; tk < 2; ++tk) {
            int kh = w * 2 + tk;
            float v = b2f(kvr[kh * 64 + lane]);
            float ss = v * v;
#pragma unroll
            for (int d = 1; d < 64; d <<= 1) ss += __shfl_xor(ss, d);
            float nrm = fmaxf(sqrtf(ss), 1e-12f);
            float g = k_gamma[kh * 64 + lane];
            kn[((size_t)(b * HH + kh) * NN + n) * 64 + lane] = f2b(v / nrm * (g + 1.0f) * 0.16f);
        }
    } else {
        const int idx = bid - 4096;
        const int bh = idx & 15;         // b*8+h
        const int b = bh >> 3, h = bh & 7;
        const int n0 = (idx >> 4) * 64;
#pragma unroll
        for (int it = 0; it < 2; ++it) {
            int id2 = tid + it * 256;
            int i = id2 >> 3, c = id2 & 7;
            short8 v = *(const short8*)&qkv[(size_t)(b * NN + n0 + i) * 2048 + 1536 + h * 64 + c * 8];
            *(short8*)&t[i * 72 + c * 8] = v;
        }
        __syncthreads();
#pragma unroll
        for (int it = 0; it < 2; ++it) {
            int id2 = tid + it * 256;
            int d = id2 >> 3, c = id2 & 7;
            const int sw = (d >> 3) & 1;
            u16 tmp[8], o[8];
#pragma unroll
            for (int j = 0; j < 8; ++j) tmp[j] = t[(c * 8 + j) * 72 + d];
#pragma unroll
            for (int j = 0; j < 8; ++j) o[j] = tmp[j ^ (sw << 2)];
            *(short8*)&vt[((size_t)(bh * 64 + d)) * NN + n0 + c * 8] = *(short8*)o;
        }
    }
}

// ---------------- flash attention v17: split-j (R18) + SINGLE-BUFFER LDS (16KB).
// 16KB/block -> all 8 dispatched blocks/CU resident (wave-cap 32/CU), 2x the
// resident TLP of the 32KB dbuf version; cross-block interleave hides the
// exposed stage->barrier latency (m97-pattern). Keeps conflict-free vf reads,
// setprio, packed-poly softmax, n-major unnormalized partials + L. ----------------
__global__ __launch_bounds__(256) void k_attn(const u16* __restrict__ qn,
                                              const u16* __restrict__ kn,
                                              const u16* __restrict__ vt,
                                              u16* __restrict__ OT,
                                              float* __restrict__ Lp) {
    const int bq = blockIdx.x;  // b*16+qh
    const int b = bq >> 4, qh = bq & 15;
    const int h = qh >> 1;
    const int tid = threadIdx.x;
    const int lane = tid & 63, w = tid >> 6;
    const int lr = lane & 15, lq = lane >> 4;
    const int y = blockIdx.y;
    const int z = 31 - (y >> 1);     // LPT: heaviest strips first
    const int s = y & 1;             // j-split half
    const int ntile = z + 1;
    const int jmid = (ntile + 1) >> 1;
    const int jb = s ? jmid : 0;
    const int je = s ? ntile : jmid;
    const int ntl = je - jb;
    const int i0 = z * 64 + w * 16;
    const int irow = i0 + lr;

    const u16* Qp = qn + (size_t)(b * QHH + qh) * NN * 64;
    const u16* Kp = kn + (size_t)(b * HH + h) * NN * 64;
    const u16* Vp = vt + (size_t)(b * HH + h) * 64 * NN;
    u16* Op = OT + (size_t)s * (BB * QHH * NN * 64) + (size_t)bq * NN * 64;  // [s][bq][n][d]
    float* Lsel = Lp + (size_t)s * (BB * QHH * NN) + (size_t)bq * NN;        // [s][bq][n]

    __shared__ __attribute__((aligned(16))) u16 Ks[64 * 64];
    __shared__ __attribute__((aligned(16))) u16 Vs[64 * 64];

    short8 qf0 = *(const short8*)&Qp[(size_t)(i0 + lr) * 64 + lq * 8];
    short8 qf1 = *(const short8*)&Qp[(size_t)(i0 + lr) * 64 + 32 + lq * 8];

    f32x4 of[4];
#pragma unroll
    for (int dt = 0; dt < 4; ++dt) of[dt] = (f32x4){0.f, 0.f, 0.f, 0.f};
    f32x2 ls = {0.f, 0.f};

    const int srow = lane >> 3;
    const int sch = (lane ^ srow) & 7;
    const int rA = w * 16, rB = w * 16 + 8;

    // incremental staging pointers, pre-offset to tile jb
    const u16* kSrcA = Kp + (size_t)jb * 4096 + (size_t)(rA + srow) * 64 + sch * 8;
    const u16* kSrcB = Kp + (size_t)jb * 4096 + (size_t)(rB + srow) * 64 + sch * 8;
    const u16* vSrcA = Vp + (size_t)(rA + srow) * NN + jb * 64 + sch * 8;
    const u16* vSrcB = Vp + (size_t)(rB + srow) * NN + jb * 64 + sch * 8;

    auto stageKV = [&]() {
        stage16(kSrcA, &Ks[rA * 64], lane);
        stage16(kSrcB, &Ks[rB * 64], lane);
        stage16(vSrcA, &Vs[rA * 64], lane);
        stage16(vSrcB, &Vs[rB * 64], lane);
        kSrcA += 64 * 64;
        kSrcB += 64 * 64;
        vSrcA += 64;
        vSrcB += 64;
    };

    // softmax on one 4-elem score fragment: x=sim/50 pre-folded; p=exp2(G(x^2)*x - c)
    auto smax = [&](f32x4 sc, int lim, bool masked) -> short4v {
        f32x2 xa = {sc[0], sc[1]};
        f32x2 xb = {sc[2], sc[3]};
        f32x2 ya = xa * xa;
        f32x2 yb = xb * xb;
        f32x2 Ga = __builtin_elementwise_fma(ya, __builtin_elementwise_fma(ya,
                       __builtin_elementwise_fma(ya, __builtin_elementwise_fma(ya,
                           sp2(0.04705711f), sp2(-0.32327190f)), sp2(1.11500760f)),
                       sp2(-2.98719110f)), sp2(9.01599730f));
        f32x2 Gb = __builtin_elementwise_fma(yb, __builtin_elementwise_fma(yb,
                       __builtin_elementwise_fma(yb, __builtin_elementwise_fma(yb,
                           sp2(0.04705711f), sp2(-0.32327190f)), sp2(1.11500760f)),
                       sp2(-2.98719110f)), sp2(9.01599730f));
        f32x2 aa = __builtin_elementwise_fma(xa, Ga, sp2(-9.0168440f));
        f32x2 ab = __builtin_elementwise_fma(xb, Gb, sp2(-9.0168440f));
        float p0 = fastexp2(aa.x);
        float p1 = fastexp2(aa.y);
        float p2 = fastexp2(ab.x);
        float p3 = fastexp2(ab.y);
        if (masked) {
            p0 = (0 <= lim) ? p0 : 0.0f;
            p1 = (1 <= lim) ? p1 : 0.0f;
            p2 = (2 <= lim) ? p2 : 0.0f;
            p3 = (3 <= lim) ? p3 : 0.0f;
        }
        ls += (f32x2){p0, p1};
        ls += (f32x2){p2, p3};
        bf16x4 pb;
        pb[0] = (__bf16)p0;
        pb[1] = (__bf16)p1;
        pb[2] = (__bf16)p2;
        pb[3] = (__bf16)p3;
        return __builtin_bit_cast(short4v, pb);
    };

    auto tile = [&](int jt) {
        const int j0 = jt << 6;
        const u16* kb = &Ks[0];
        const u16* vb = &Vs[0];
        f32x4 sc[4];
        __builtin_amdgcn_s_setprio(1);
#pragma unroll
        for (int ct = 0; ct < 4; ++ct) {
            const int r = ct * 16 + lr;
            short8 kf0 = *(const short8*)&kb[r * 64 + ((lq ^ (lr & 7)) << 3)];
            short8 kf1 = *(const short8*)&kb[r * 64 + (((4 + lq) ^ (lr & 7)) << 3)];
            f32x4 t = (f32x4){0.f, 0.f, 0.f, 0.f};
            t = mfma16(kf0, qf0, t);
            t = mfma16(kf1, qf1, t);
            sc[ct] = t;
        }
        __builtin_amdgcn_s_setprio(0);
        const bool masked = (jt == ntile - 1);
        short4v pk[4];
#pragma unroll
        for (int ct = 0; ct < 4; ++ct) {
            const int lim = irow - (j0 + ct * 16 + lq * 4);
            pk[ct] = smax(sc[ct], lim, masked);
        }
        __builtin_amdgcn_s_setprio(1);
#pragma unroll
        for (int dt = 0; dt < 4; ++dt) {
            const int d = dt * 16 + lr;
#pragma unroll
            for (int ct = 0; ct < 4; ++ct) {
                short4v vf = *(const short4v*)
                    &vb[d * 64 + ((((ct << 1) + (lq >> 1)) ^ (lr & 7)) << 3) +
                        (((lq ^ (lr >> 3)) & 1) << 2)];
                of[dt] = mfma_k16(vf, pk[ct], of[dt]);
            }
        }
        __builtin_amdgcn_s_setprio(0);
    };

    for (int t = 0; t < ntl; ++t) {
        __syncthreads();          // WAR: prior tile's LDS reads complete
        stageKV();
        __syncthreads();          // staged data visible
        tile(jb + t);
    }

    float l = ls.x + ls.y;
    l += __shfl_xor(l, 16);
    l += __shfl_xor(l, 32);
    // write UNNORMALIZED partial O (bf16, n-major) + partial l (one per row)
#pragma unroll
    for (int dt = 0; dt < 4; ++dt) {
        u16 o[4];
#pragma unroll
        for (int r = 0; r < 4; ++r) o[r] = f2b(of[dt][r]);
        *(ushort4*)&Op[(size_t)irow * 64 + dt * 16 + lq * 4] = *(ushort4*)o;
    }
    if (lq == 0) Lsel[irow] = l;
}

// ---------------- combine splits+groups (n-major partials):
// AO[b,n,hh*64+d] = (Oa0+Ob0)/(la0+lb0) + (Oa1+Ob1)/(la1+lb1)
// fully coalesced elementwise, no LDS ----------------
__global__ __launch_bounds__(256) void k_gsum(const u16* __restrict__ O,
                                              const float* __restrict__ Lp,
                                              u16* __restrict__ AO) {
    const int idx = blockIdx.x * 256 + threadIdx.x;   // 8B chunk id: [b][n][c8]
    const int c8 = idx & 63;
    const int n = (idx >> 6) & 2047;
    const int b = idx >> 17;
    const int hh = c8 >> 3;
    const int ch = c8 & 7;
    const int q0 = b * QHH + 2 * hh, q1 = q0 + 1;
    const size_t SOFF = (size_t)BB * QHH * NN * 64;   // s=1 O offset (u16 units)
    const size_t LOFF = (size_t)BB * QHH * NN;        // s=1 L offset (floats)
    const u16* a0 = O + ((size_t)q0 * NN + n) * 64 + ch * 8;
    const u16* a1 = O + ((size_t)q1 * NN + n) * 64 + ch * 8;
    const u16* b0 = a0 + SOFF;
    const u16* b1 = a1 + SOFF;
    const float l0 = Lp[(size_t)q0 * NN + n] + Lp[LOFF + (size_t)q0 * NN + n];
    const float l1 = Lp[(size_t)q1 * NN + n] + Lp[LOFF + (size_t)q1 * NN + n];
    const float inv0 = fastrcp(l0);
    const float inv1 = fastrcp(l1);
    short8 va0 = *(const short8*)a0;
    short8 vb0 = *(const short8*)b0;
    short8 va1 = *(const short8*)a1;
    short8 vb1 = *(const short8*)b1;
    u16 o[8];
#pragma unroll
    for (int j = 0; j < 8; ++j)
        o[j] = f2b((b2f((u16)va0[j]) + b2f((u16)vb0[j])) * inv0 +
                   (b2f((u16)va1[j]) + b2f((u16)vb1[j])) * inv1);
    *(short8*)&AO[((size_t)(b * NN + n)) * 512 + c8 * 8] = *(short8*)o;
}

extern "C" void kernel_launch(void* const* d_in, const int* in_sizes, int n_in,
                              void* d_out, int out_size, void* d_ws, size_t ws_size,
                              hipStream_t stream) {
    const float* tokens = (const float*)d_in[0];
    const float* norm_w = (const float*)d_in[1];
    const float* Wq = (const float*)d_in[2];
    const float* Wkv = (const float*)d_in[3];
    const float* Wout = (const float*)d_in[4];
    const float* q_gamma = (const float*)d_in[5];
    const float* k_gamma = (const float*)d_in[6];
    float* out = (float*)d_out;

    char* ws = (char*)d_ws;
    u16* xb = (u16*)(ws + 0);             // 8 MB  [4096,1024]
    u16* WqT = (u16*)(ws + 8388608);      // 2 MB  } adjacent => fused Bt [2048][1024]
    u16* WkvT = (u16*)(ws + 10485760);    // 2 MB  }
    u16* WoutT = (u16*)(ws + 12582912);   // 1 MB
    u16* qkv = (u16*)(ws + 13631488);     // 16 MB fused [4096][2048] (q_raw ∪ kv_raw)
    u16* kn = (u16*)(ws + 30408704);      // 4 MB
    u16* vtb = (u16*)(ws + 34603008);     // 4 MB
    // Lifetime aliases (stream-ordered, no overlap):
    u16* qn = xb;                       // xb dead after fused QKV GEMM
    u16* Opart = qkv;                   // 16 MB: [s=0]8MB @13631488 + [s=1]8MB @22020096 (qkv dead)
    float* Lpart = (float*)(ws + 8388608);  // 512 KB in dead WqT/WkvT region (dead after gemm128)
    u16* AO = kn;                       // 4 MB: kn dead after attn; AO written by gsum after attn

    k_pre<<<7168, 256, 0, stream>>>(tokens, norm_w, xb, Wq, Wkv, Wout, WqT, WkvT, WoutT);
    // fused QKV GEMM: [4096,1024] x [2048,1024]^T -> [4096,2048]
    k_gemm128<<<dim3(16, 32), 256, 0, stream>>>(xb, WqT, qkv, 4096, 2048, 1024);
    k_mid<<<4608, 256, 0, stream>>>(qkv, q_gamma, k_gamma, qn, kn, vtb);
    k_attn<<<dim3(32, 64), 256, 0, stream>>>(qn, kn, vtb, Opart, Lpart);
    k_gsum<<<1024, 256, 0, stream>>>(Opart, Lpart, AO);
    k_gemm64f<<<dim3(8, 64), 256, 0, stream>>>(AO, WoutT, out, 4096, 1024, 512);
}